// Round 12
// baseline (146.837 us; speedup 1.0000x reference)
//
#include <hip/hip_runtime.h>

// ---------------------------------------------------------------------------
// CustomDeformableDetrMLPPredictionHead — MI355X (gfx950), round 11.
// Round-10 structure; k_fused barrier surgery:
//   KEY FACT: wave wv reads only Pt rows [wv*64, wv*64+64) and thread
//   t = wv*64+lane stages exactly row t  =>  Pt staging is wave-private.
//   The 3 staging barriers synchronized nothing cross-wave; removed.
//   Remaining barriers: gates-visible, pre-X-overwrite (Pt/X union),
//   X-visible, red-reduce  (8 -> 4 all-wave drain points per block).
// Intra-wave LDS write->read ordering is guaranteed by the in-order DS pipe
// + compiler lgkmcnt (it cannot prove non-aliasing on sm.Pt, so it orders).
// ---------------------------------------------------------------------------

typedef _Float16 half8 __attribute__((ext_vector_type(8)));
typedef _Float16 half4v __attribute__((ext_vector_type(4)));
typedef float floatx4 __attribute__((ext_vector_type(4)));

#define MFMA16(a, b, c) __builtin_amdgcn_mfma_f32_16x16x32_f16((a), (b), (c), 0, 0, 0)

// ---------------- k_wprep: mats 0..15 -> MFMA f16 tiles (verified) ---------
__global__ __launch_bounds__(256) void k_wprep(
    const float* __restrict__ Wq, const float* __restrict__ Wk,
    const float* __restrict__ Wsub, const float* __restrict__ Wobj,
    const float* __restrict__ W1, _Float16* __restrict__ WT)
{
    int eid = blockIdx.x * 256 + threadIdx.x;     // 0..131071
    int mat = eid >> 13;                          // 0..15
    int rem = eid & 8191;
    int tileid = rem >> 6;
    int lane = rem & 63;
    const float* src;
    if      (mat < 6)  src = Wq + mat * 65536;
    else if (mat < 12) src = Wk + (mat - 6) * 65536;
    else if (mat == 12) src = Wsub;
    else if (mat == 13) src = Wobj;
    else if (mat == 14) src = W1;            // W1a: rows 0..255
    else               src = W1 + 65536;     // W1b: rows 256..511
    int nb = tileid >> 3, kb = tileid & 7;
    int n = nb * 16 + (lane & 15);
    int k = kb * 32 + (lane >> 4) * 8;
    half8 h;
    #pragma unroll
    for (int j = 0; j < 8; ++j) h[j] = (_Float16)src[(k + j) * 256 + n];
    *(half8*)(WT + mat * 65536 + tileid * 512 + lane * 8) = h;
}

// ---------------- k_projpq: M=16, 532 blocks + 32 W2-pack blocks -----------
__global__ __launch_bounds__(256) void k_projpq(
    const float* __restrict__ hs, _Float16* __restrict__ WT,
    const float* __restrict__ bq, const float* __restrict__ bk,
    const float* __restrict__ bsub, const float* __restrict__ bobj,
    const float* __restrict__ Wg, const float* __restrict__ W2,
    _Float16* __restrict__ PQt, _Float16* __restrict__ PKt,
    float* __restrict__ g_ws)
{
    int t = threadIdx.x;
    if (blockIdx.x >= 532) {           // W2 pack tail (verified pattern)
        int eid = (blockIdx.x - 532) * 256 + t;   // 0..8191
        int tileid = eid >> 6, lane = eid & 63;
        int nb = tileid >> 3, kb = tileid & 7;
        int n = nb * 16 + (lane & 15);
        int k = kb * 32 + (lane >> 4) * 8;
        half8 h;
        #pragma unroll
        for (int j = 0; j < 8; ++j) h[j] = (_Float16)W2[(k + j) * 256 + n];
        *(half8*)(WT + 16 * 65536 + tileid * 512 + lane * 8) = h;
        return;
    }

    __shared__ __align__(16) _Float16 Ah[16][264];   // hs f16; reused as Pst
    __shared__ __align__(16) _Float16 Xb[16][264];   // Q f16

    int lane = t & 63, wv = t >> 6;
    int mr = lane & 15, hf = lane >> 4;
    int u = blockIdx.x;
    int s = u / 19, rt = u - s * 19;
    int m0 = rt * 16;
    int qk = s & 1, rr = s >> 1;
    int l = rr % 7, b = rr / 7;
    int hs_l = (l < 6) ? l : 5;
    const float* src = hs + (hs_l * 2 + b) * 76800;
    int projmat = (l < 6) ? (qk * 6 + l) : (12 + qk);
    const _Float16* WprojT = WT + projmat * 65536;
    const _Float16* W1hT = WT + (14 + qk) * 65536;
    const float* bias = (l < 6) ? ((qk ? bk : bq) + l * 256) : (qk ? bobj : bsub);
    _Float16* dstP = qk ? PKt : PQt;
    const float* wvec = Wg + qk * 256;
    float* gdst = g_ws + qk * 4200 + (l * 2 + b) * 300;

    // stage 16 hs rows -> Ah f16 (16 threads/row, 16 cols each)
    {
        int row = t >> 4, qt = t & 15;
        int m = m0 + row; if (m > 299) m = 299;   // clamp; masked later
        const float* pp = src + m * 256 + qt * 16;
        #pragma unroll
        for (int i = 0; i < 4; ++i) {
            float4 v = *(const float4*)(pp + 4 * i);
            half4v h;
            h[0] = (_Float16)v.x; h[1] = (_Float16)v.y;
            h[2] = (_Float16)v.z; h[3] = (_Float16)v.w;
            *(half4v*)&Ah[row][qt * 16 + 4 * i] = h;
        }
    }
    __syncthreads();

    // GEMM1 (flipped): Q^T = Wproj^T @ hs^T
    floatx4 acc[4];
    #pragma unroll
    for (int i = 0; i < 4; ++i) acc[i] = floatx4{0.f, 0.f, 0.f, 0.f};
    #pragma unroll
    for (int ks = 0; ks < 8; ++ks) {
        half8 bfr = *(const half8*)&Ah[mr][ks * 32 + hf * 8];
        #pragma unroll
        for (int mt = 0; mt < 4; ++mt) {
            half8 afr = *(const half8*)(WprojT + (((wv * 4 + mt) * 8 + ks) << 9) + lane * 8);
            acc[mt] = MFMA16(afr, bfr, acc[mt]);
        }
    }
    #pragma unroll
    for (int mt = 0; mt < 4; ++mt) {
        int n0 = wv * 64 + mt * 16 + hf * 4;
        float4 bb = *(const float4*)&bias[n0];
        float bv[4] = {bb.x, bb.y, bb.z, bb.w};
        half4v h;
        #pragma unroll
        for (int u2 = 0; u2 < 4; ++u2) h[u2] = (_Float16)(acc[mt][u2] + bv[u2]);
        *(half4v*)&Xb[mr][n0] = h;
    }
    __syncthreads();

    // gq/gk row dots
    {
        int row = t >> 4, qt = t & 15;
        half8 x0 = *(const half8*)&Xb[row][qt * 16];
        half8 x1 = *(const half8*)&Xb[row][qt * 16 + 8];
        const float* wp = wvec + qt * 16;
        float sum = 0.f;
        #pragma unroll
        for (int i = 0; i < 8; ++i) sum += (float)x0[i] * wp[i];
        #pragma unroll
        for (int i = 0; i < 8; ++i) sum += (float)x1[i] * wp[8 + i];
        sum += __shfl_xor(sum, 1);
        sum += __shfl_xor(sum, 2);
        sum += __shfl_xor(sum, 4);
        sum += __shfl_xor(sum, 8);
        int m = m0 + row;
        if (qt == 0 && m < 300) gdst[m] = sum;
    }

    // GEMM2 (flipped): P^T = W1h^T @ Q^T
    floatx4 acc2[4];
    #pragma unroll
    for (int i = 0; i < 4; ++i) acc2[i] = floatx4{0.f, 0.f, 0.f, 0.f};
    #pragma unroll
    for (int ks = 0; ks < 8; ++ks) {
        half8 bfr = *(const half8*)&Xb[mr][ks * 32 + hf * 8];
        #pragma unroll
        for (int mt = 0; mt < 4; ++mt) {
            half8 afr = *(const half8*)(W1hT + (((wv * 4 + mt) * 8 + ks) << 9) + lane * 8);
            acc2[mt] = MFMA16(afr, bfr, acc2[mt]);
        }
    }
    #pragma unroll
    for (int mt = 0; mt < 4; ++mt) {
        int n0 = wv * 64 + mt * 16 + hf * 4;
        half4v h;
        #pragma unroll
        for (int u2 = 0; u2 < 4; ++u2) h[u2] = (_Float16)acc2[mt][u2];
        *(half4v*)&Ah[mr][n0] = h;   // Pst reuse
    }
    __syncthreads();

    // coalesced store, l-major layout:
    //   dst[(((b*38+it)*7 + l)*256 + n)*8 + io], wave writes 1KB contiguous
    #pragma unroll
    for (int z = 0; z < 2; ++z) {
        int it = rt * 2 + z;
        int n = t;
        half8 h;
        #pragma unroll
        for (int io = 0; io < 8; ++io) h[io] = Ah[z * 8 + io][n];
        *(half8*)(dstP + ((size_t)((b * 38 + it) * 7 + l) * 256 + n) * 8) = h;
    }
}

// ---------------- k_fused: wave-private Pt staging, 4 barriers -------------
// grid 2*38*38 = 2888, block 256 (4 waves; waves split 256 out-cols).
// LDS: union{Pt 36.9KB, X 33.8KB} + gate 1.8KB = 38.7KB -> 4 blocks/CU.
__global__ __launch_bounds__(256, 4) void k_fused(
    const _Float16* __restrict__ PQt, const _Float16* __restrict__ PKt,
    const float* __restrict__ g_ws, const float* __restrict__ b1,
    const _Float16* __restrict__ W2T, const float* __restrict__ b2,
    const float* __restrict__ W3, const float* __restrict__ b3,
    const float* __restrict__ bg, float* __restrict__ out)
{
    union SM {
        _Float16 Pt[256][72];   // [n][k], k = l*8+io (0..55); 56..63 zero pad
        _Float16 X[64][264];    // [r][col]
    };
    __shared__ __align__(16) SM sm;
    __shared__ float gate[7][64];   // gates; reused as red[4][64] at the end

    int t = threadIdx.x, lane = t & 63, wv = t >> 6;
    int mr = lane & 15, hf = lane >> 4;
    int bid = blockIdx.x;
    int b = bid / 1444, rem = bid - b * 1444;
    int it = rem / 38, jt = rem - it * 38;
    int i0 = it * 8, j0 = jt * 8;

    // ---- prefetch both P slices (L2 latency overlaps gate math) ----
    const _Float16* baseQ = PQt + ((size_t)((b * 38 + it) * 7) * 256 + t) * 8;
    const _Float16* baseK = PKt + ((size_t)((b * 38 + jt) * 7) * 256 + t) * 8;
    half8 pq[7], pk[7];
    #pragma unroll
    for (int l = 0; l < 7; ++l) pq[l] = *(const half8*)(baseQ + l * 2048);
    #pragma unroll
    for (int l = 0; l < 7; ++l) pk[l] = *(const half8*)(baseK + l * 2048);

    // ---- gates: gate[l][r], r = (i_off<<3)|j_off (verified) ----
    float bg0 = bg[0];
    for (int task = t; task < 448; task += 256) {
        int l = task >> 6, row = task & 63;
        int i = i0 + (row >> 3); if (i > 299) i = 299;
        int j = j0 + (row & 7);  if (j > 299) j = 299;
        float z = g_ws[l * 600 + b * 300 + i] + g_ws[4200 + l * 600 + b * 300 + j] + bg0;
        gate[l][row] = 1.0f / (1.0f + __expf(-z));
    }

    // ---- stage PQ -> Pt.  Thread t writes row t; wave wv reads only rows
    //      [wv*64, wv*64+64)  =>  staging is WAVE-PRIVATE: no barrier needed
    //      for Pt itself.  The single barrier below is for the gates.
    #pragma unroll
    for (int l = 0; l < 7; ++l)
        *(half8*)&sm.Pt[t][l * 8] = pq[l];
    *(half8*)&sm.Pt[t][56] = half8{};   // zero pad (persists for pass 1)
    __syncthreads();   // BARRIER 1: gates visible (Pt needs none)

    floatx4 acc1[4][4];
    #pragma unroll
    for (int i = 0; i < 4; ++i)
        #pragma unroll
        for (int j = 0; j < 4; ++j) acc1[i][j] = floatx4{0.f, 0.f, 0.f, 0.f};

    // ---- pass 0 (out_q): B one-hot jstar = nt*2 + (mr>>3) ----
    #pragma unroll
    for (int ktl = 0; ktl < 2; ++ktl) {
        int l = ktl * 4 + hf;
        half8 bfr[4];
        #pragma unroll
        for (int nt = 0; nt < 4; ++nt) {
            int r = nt * 16 + mr;
            float g = (l < 7) ? gate[l][r] : 0.f;
            _Float16 gh = (_Float16)g;
            const _Float16 hz = (_Float16)0.f;
            half8 f = {};
            f[nt * 2]     = (mr < 8)  ? gh : hz;
            f[nt * 2 + 1] = (mr >= 8) ? gh : hz;
            bfr[nt] = f;
        }
        #pragma unroll
        for (int mt = 0; mt < 4; ++mt) {
            half8 afr = *(const half8*)&sm.Pt[wv * 64 + mt * 16 + mr][ktl * 32 + hf * 8];
            #pragma unroll
            for (int nt = 0; nt < 4; ++nt)
                acc1[mt][nt] = MFMA16(afr, bfr[nt], acc1[mt][nt]);
        }
    }
    // NO BARRIER: pass-0 reads and PK staging below touch only this wave's
    // Pt rows; in-order DS pipe + compiler lgkmcnt give intra-wave ordering.

    // ---- stage PK -> Pt (wave-private, reg->LDS) ----
    #pragma unroll
    for (int l = 0; l < 7; ++l)
        *(half8*)&sm.Pt[t][l * 8] = pk[l];
    // NO BARRIER: same wave-ownership argument.

    // ---- pass 1 (out_k): B one-hot jstar = mr & 7 ----
    #pragma unroll
    for (int ktl = 0; ktl < 2; ++ktl) {
        int l = ktl * 4 + hf;
        half8 bfr[4];
        #pragma unroll
        for (int nt = 0; nt < 4; ++nt) {
            int r = nt * 16 + mr;
            float g = (l < 7) ? gate[l][r] : 0.f;
            _Float16 gh = (_Float16)g;
            const _Float16 hz = (_Float16)0.f;
            half8 f = {};
            #pragma unroll
            for (int j = 0; j < 8; ++j)
                f[j] = (j == (mr & 7)) ? gh : hz;
            bfr[nt] = f;
        }
        #pragma unroll
        for (int mt = 0; mt < 4; ++mt) {
            half8 afr = *(const half8*)&sm.Pt[wv * 64 + mt * 16 + mr][ktl * 32 + hf * 8];
            #pragma unroll
            for (int nt = 0; nt < 4; ++nt)
                acc1[mt][nt] = MFMA16(afr, bfr[nt], acc1[mt][nt]);
        }
    }
    __syncthreads();   // BARRIER 2: all waves' Pt+gate reads done before the
                       // X union overwrite (X rows alias other waves' Pt)

    // ---- epilogue 1: relu(x1 + b1) -> X[r][n], packed b64 ----
    #pragma unroll
    for (int mt = 0; mt < 4; ++mt) {
        int n0 = wv * 64 + mt * 16 + hf * 4;
        float4 bb = *(const float4*)&b1[n0];
        float bv[4] = {bb.x, bb.y, bb.z, bb.w};
        #pragma unroll
        for (int nt = 0; nt < 4; ++nt) {
            int r = nt * 16 + mr;
            half4v h;
            #pragma unroll
            for (int u = 0; u < 4; ++u) {
                float v = acc1[mt][nt][u] + bv[u];
                h[u] = (_Float16)(v > 0.f ? v : 0.f);
            }
            *(half4v*)&sm.X[r][n0] = h;
        }
    }
    __syncthreads();   // BARRIER 3: X visible to all waves (cross-wave read)

    // ---- layer 2 (flipped): x2^T = W2^T @ x1^T ----
    floatx4 acc2[4][4];
    #pragma unroll
    for (int i = 0; i < 4; ++i)
        #pragma unroll
        for (int j = 0; j < 4; ++j) acc2[i][j] = floatx4{0.f, 0.f, 0.f, 0.f};
    for (int s = 0; s < 8; ++s) {
        half8 bfr[4];
        #pragma unroll
        for (int nt = 0; nt < 4; ++nt)
            bfr[nt] = *(const half8*)&sm.X[nt * 16 + mr][s * 32 + hf * 8];
        #pragma unroll
        for (int mt = 0; mt < 4; ++mt) {
            half8 afr = *(const half8*)(W2T + (((wv * 4 + mt) * 8 + s) << 9) + lane * 8);
            #pragma unroll
            for (int nt = 0; nt < 4; ++nt)
                acc2[mt][nt] = MFMA16(afr, bfr[nt], acc2[mt][nt]);
        }
    }

    // ---- fused epilogue 2 + layer 3: p[row] = relu(x2+b2) . W3 ----
    {
        float* red = &gate[0][0];            // 256 floats; gates are dead
        float p[4] = {0.f, 0.f, 0.f, 0.f};
        #pragma unroll
        for (int mt = 0; mt < 4; ++mt) {
            int n0 = wv * 64 + mt * 16 + hf * 4;
            float4 bb = *(const float4*)&b2[n0];
            float4 w3 = *(const float4*)&W3[n0];
            float bv[4] = {bb.x, bb.y, bb.z, bb.w};
            float wv3[4] = {w3.x, w3.y, w3.z, w3.w};
            #pragma unroll
            for (int nt = 0; nt < 4; ++nt)
                #pragma unroll
                for (int u = 0; u < 4; ++u) {
                    float v = acc2[mt][nt][u] + bv[u];
                    v = v > 0.f ? v : 0.f;
                    p[nt] += v * wv3[u];
                }
        }
        #pragma unroll
        for (int nt = 0; nt < 4; ++nt) {
            p[nt] += __shfl_xor(p[nt], 16);
            p[nt] += __shfl_xor(p[nt], 32);
        }
        if (hf == 0) {
            #pragma unroll
            for (int nt = 0; nt < 4; ++nt)
                red[wv * 64 + nt * 16 + mr] = p[nt];
        }
        __syncthreads();   // BARRIER 4: red partials visible
        if (t < 64) {
            float pred = red[t] + red[64 + t] + red[128 + t] + red[192 + t] + b3[0];
            int i = i0 + (t >> 3), j = j0 + (t & 7);
            if (i < 300 && j < 300) {
                int base = b * 90000 + i * 300 + j;
                #pragma unroll
                for (int lo = 0; lo < 6; ++lo) out[lo * 180000 + base] = pred;
            }
        }
    }
}

// ---------------------------------------------------------------------------
extern "C" void kernel_launch(void* const* d_in, const int* in_sizes, int n_in,
                              void* d_out, int out_size, void* d_ws, size_t ws_size,
                              hipStream_t stream) {
    (void)in_sizes; (void)n_in; (void)out_size; (void)ws_size;
    const float* hs   = (const float*)d_in[0];
    const float* Wq   = (const float*)d_in[1];
    const float* bq   = (const float*)d_in[2];
    const float* Wk   = (const float*)d_in[3];
    const float* bk   = (const float*)d_in[4];
    const float* Wsub = (const float*)d_in[5];
    const float* bsub = (const float*)d_in[6];
    const float* Wobj = (const float*)d_in[7];
    const float* bobj = (const float*)d_in[8];
    const float* Wg   = (const float*)d_in[9];
    const float* bg   = (const float*)d_in[10];
    const float* W1   = (const float*)d_in[11];
    const float* b1   = (const float*)d_in[12];
    const float* W2   = (const float*)d_in[13];
    const float* b2   = (const float*)d_in[14];
    const float* W3   = (const float*)d_in[15];
    const float* b3   = (const float*)d_in[16];

    char* ws = (char*)d_ws;
    float* g_ws   = (float*)ws;                  // 8,400 f
    _Float16* WT  = (_Float16*)(ws + 33600);     // 17*65536 h
    _Float16* PQt = WT + 17 * 65536;             // 1,089,536 h (l-major layout)
    _Float16* PKt = PQt + 1089536;               // 1,089,536 h

    k_wprep<<<512, 256, 0, stream>>>(Wq, Wk, Wsub, Wobj, W1, WT);
    k_projpq<<<564, 256, 0, stream>>>(hs, WT, bq, bk, bsub, bobj, Wg, W2,
                                      PQt, PKt, g_ws);
    k_fused<<<2888, 256, 0, stream>>>(PQt, PKt, g_ws, b1, WT + 16 * 65536,
                                      b2, W3, b3, bg, (float*)d_out);
}